// Round 8
// baseline (767.486 us; speedup 1.0000x reference)
//
#include <hip/hip_runtime.h>
#include <hip/hip_bf16.h>

typedef __hip_bfloat16 bf16;
typedef __attribute__((ext_vector_type(8))) short short8v;
typedef __attribute__((ext_vector_type(4))) float f32x4;

__device__ __forceinline__ float b2f(bf16 v){ return __bfloat162float(v); }
__device__ __forceinline__ bf16 f2b(float v){ return __float2bfloat16(v); }
__device__ __forceinline__ float softplus_f(float x){ return (x > 15.f) ? x : __logf(1.f + __expf(x)); }
__device__ __forceinline__ float sigmoid_f(float x){ return 1.f / (1.f + __expf(-x)); }

// ---------------- embedding: fea[n,d] = sum_k A[n,k] * W_emb[d,k] ----------------
__global__ __launch_bounds__(256) void k_embed(const float* __restrict__ A, const float* __restrict__ W,
                                               float* __restrict__ fea){
  __shared__ float Wl[92][64];
  __shared__ float Al[64][92];
  int t = threadIdx.x;
  int base = blockIdx.x * 64;
  for (int i = t; i < 92*64; i += 256){ int d = i / 92, k = i - d*92; Wl[k][d] = W[d*92 + k]; }
  for (int i = t; i < 64*92; i += 256){ int a = i / 92, k = i - a*92; Al[a][k] = A[(size_t)(base+a)*92 + k]; }
  __syncthreads();
  int d = t & 63, slot = t >> 6;
  for (int a = slot; a < 64; a += 4){
    float acc = 0.f;
    #pragma unroll 4
    for (int k = 0; k < 92; k++) acc += Al[a][k] * Wl[k][d];
    fea[(size_t)(base+a)*64 + d] = acc;
  }
}

// ---------------- proj via MFMA: P[a][c] = fea[a,:].Wcat[c,:] (kept — round-7 win) ----------------
__global__ __launch_bounds__(256) void k_proj(const float* __restrict__ fea, const float* __restrict__ W,
                                              float* __restrict__ P){
  __shared__ bf16 Fb[64][72];
  __shared__ bf16 Wb[256][72];
  int t = threadIdx.x, L = t & 63, w = t >> 6;
  int base = blockIdx.x * 64;
  for (int i = t; i < 4096; i += 256){ int r = i >> 6, d = i & 63;
    Fb[r][d] = f2b(fea[(size_t)(base+r)*64 + d]); }
  for (int i = t; i < 16384; i += 256){ int rw = i >> 6, e = i & 63;
    Wb[rw][e] = f2b(W[(size_t)(rw & 127)*169 + ((rw < 128) ? 0 : 64) + e]); }
  __syncthreads();
  short8v av0 = *(const short8v*)&Fb[w*16 + (L&15)][(L>>4)*8];
  short8v av1 = *(const short8v*)&Fb[w*16 + (L&15)][(L>>4)*8 + 32];
  #pragma unroll
  for (int tc = 0; tc < 16; tc++){
    short8v bv0 = *(const short8v*)&Wb[tc*16 + (L&15)][(L>>4)*8];
    short8v bv1 = *(const short8v*)&Wb[tc*16 + (L&15)][(L>>4)*8 + 32];
    f32x4 acc = (f32x4){0.f,0.f,0.f,0.f};
    acc = __builtin_amdgcn_mfma_f32_16x16x32_bf16(av0, bv0, acc, 0, 0, 0);
    acc = __builtin_amdgcn_mfma_f32_16x16x32_bf16(av1, bv1, acc, 0, 0, 0);
    #pragma unroll
    for (int r = 0; r < 4; r++){
      int m = base + w*16 + (L>>4)*4 + r;
      P[(size_t)m*256 + tc*16 + (L&15)] = acc[r];
    }
  }
}

// ---------------- gate: round-3 structure + 8-way acc split + 2048-block grid ----------------
__global__ __launch_bounds__(256) void k_gate(const float* __restrict__ P, const float* __restrict__ nbrF,
    const int* __restrict__ idx, const float* __restrict__ W, const float* __restrict__ bg,
    bf16* __restrict__ gated, float* __restrict__ psum, float* __restrict__ psq){
  __shared__ float nf[24][44];
  __shared__ int jrow[24];
  __shared__ float red[256];
  int t = threadIdx.x;
  int slot = t >> 7, c = t & 127;
  float wreg[41];
  #pragma unroll
  for (int e = 0; e < 41; e++) wreg[e] = W[(size_t)c*169 + 128 + e];
  float bv = bg[c];
  float s = 0.f, q = 0.f;
  int rbase = blockIdx.x * 144;
  for (int st = 0; st < 6; st++){
    int row0 = rbase + st*24;
    __syncthreads();
    for (int i = t; i < 24*41; i += 256){ int rr = i / 41, e = i - rr*41; nf[rr][e] = nbrF[(size_t)(row0+rr)*41 + e]; }
    if (t < 24) jrow[t] = idx[row0 + t];
    __syncthreads();
    int a = row0/12 + slot;
    float ps = P[(size_t)a*256 + c] + bv;
    #pragma unroll
    for (int m = 0; m < 12; m++){
      int rr = slot*12 + m;
      int j = jrow[rr];
      float pn = P[(size_t)j*256 + 128 + c];
      float ac0=0.f, ac1=0.f, ac2=0.f, ac3=0.f, ac4=0.f, ac5=0.f, ac6=0.f, ac7=0.f;
      {
        float4 n0 = *(const float4*)&nf[rr][0];
        float4 n1 = *(const float4*)&nf[rr][4];
        float4 n2 = *(const float4*)&nf[rr][8];
        float4 n3 = *(const float4*)&nf[rr][12];
        float4 n4 = *(const float4*)&nf[rr][16];
        float4 n5 = *(const float4*)&nf[rr][20];
        float4 n6 = *(const float4*)&nf[rr][24];
        float4 n7 = *(const float4*)&nf[rr][28];
        float4 n8 = *(const float4*)&nf[rr][32];
        float4 n9 = *(const float4*)&nf[rr][36];
        ac0 += n0.x*wreg[0]  + n0.y*wreg[1]  + n0.z*wreg[2]  + n0.w*wreg[3];
        ac1 += n1.x*wreg[4]  + n1.y*wreg[5]  + n1.z*wreg[6]  + n1.w*wreg[7];
        ac2 += n2.x*wreg[8]  + n2.y*wreg[9]  + n2.z*wreg[10] + n2.w*wreg[11];
        ac3 += n3.x*wreg[12] + n3.y*wreg[13] + n3.z*wreg[14] + n3.w*wreg[15];
        ac4 += n4.x*wreg[16] + n4.y*wreg[17] + n4.z*wreg[18] + n4.w*wreg[19];
        ac5 += n5.x*wreg[20] + n5.y*wreg[21] + n5.z*wreg[22] + n5.w*wreg[23];
        ac6 += n6.x*wreg[24] + n6.y*wreg[25] + n6.z*wreg[26] + n6.w*wreg[27];
        ac7 += n7.x*wreg[28] + n7.y*wreg[29] + n7.z*wreg[30] + n7.w*wreg[31];
        ac0 += n8.x*wreg[32] + n8.y*wreg[33] + n8.z*wreg[34] + n8.w*wreg[35];
        ac1 += n9.x*wreg[36] + n9.y*wreg[37] + n9.z*wreg[38] + n9.w*wreg[39];
        ac2 += nf[rr][40]*wreg[40];
      }
      float acc = ps + pn + (((ac0+ac1)+(ac2+ac3)) + ((ac4+ac5)+(ac6+ac7)));
      gated[(size_t)(row0+rr)*128 + c] = f2b(acc);
      s += acc; q += acc*acc;
    }
  }
  red[t] = s; __syncthreads();
  if (t < 128) psum[blockIdx.x*128 + t] = red[t] + red[t+128];
  __syncthreads(); red[t] = q; __syncthreads();
  if (t < 128) psq[blockIdx.x*128 + t] = red[t] + red[t+128];
}

__global__ __launch_bounds__(1024) void k_fin1(const float* __restrict__ ps, const float* __restrict__ pq,
    const float* __restrict__ g, const float* __restrict__ be, float* __restrict__ scale, float* __restrict__ shift){
  __shared__ float rs[1024], rq[1024];
  int t = threadIdx.x, c = t & 127, gi = t >> 7;
  float s = 0.f, q = 0.f;
  for (int b = gi; b < 2048; b += 8){ s += ps[b*128 + c]; q += pq[b*128 + c]; }
  rs[t] = s; rq[t] = q; __syncthreads();
  if (t < 128){
    float S = 0.f, Q = 0.f;
    #pragma unroll
    for (int gg = 0; gg < 8; gg++){ S += rs[gg*128 + t]; Q += rq[gg*128 + t]; }
    float cnt = 294912.0f;
    float mu = S / cnt;
    float var = Q / cnt - mu*mu;
    float sc = rsqrtf(var + 1e-5f) * g[t];
    scale[t] = sc;
    shift[t] = be[t] - mu * sc;
  }
}

// ---------------- pool: vectorized (short8) normalize + sigmoid*softplus + sum over M ----------------
__global__ __launch_bounds__(256) void k_pool(const bf16* __restrict__ gated, const float* __restrict__ scale,
    const float* __restrict__ shift, float* __restrict__ summed, float* __restrict__ psum, float* __restrict__ psq){
  __shared__ float sc[128], sh[128];
  __shared__ float sb[32][65], qb[32][65];
  int t = threadIdx.x;
  if (t < 128){ sc[t] = scale[t]; sh[t] = shift[t]; }
  __syncthreads();
  int nl = t >> 3, jb = t & 7;
  int n = blockIdx.x*32 + nl;
  const bf16* gp = gated + (size_t)n*1536 + jb*8;
  float sc1r[8], sh1r[8], sc2r[8], sh2r[8];
  #pragma unroll
  for (int k = 0; k < 8; k++){
    int d = jb*8 + k;
    sc1r[k] = sc[d]; sh1r[k] = sh[d]; sc2r[k] = sc[64+d]; sh2r[k] = sh[64+d];
  }
  float acc[8];
  #pragma unroll
  for (int k = 0; k < 8; k++) acc[k] = 0.f;
  #pragma unroll
  for (int m = 0; m < 12; m++){
    short8v fv = *(const short8v*)(gp + m*128);
    short8v cv = *(const short8v*)(gp + m*128 + 64);
    #pragma unroll
    for (int k = 0; k < 8; k++){
      bf16 fb, cb;
      *(short*)&fb = fv[k]; *(short*)&cb = cv[k];
      float y1 = b2f(fb) * sc1r[k] + sh1r[k];
      float y2 = b2f(cb) * sc2r[k] + sh2r[k];
      acc[k] += sigmoid_f(y1) * softplus_f(y2);
    }
  }
  float* sp = &summed[(size_t)n*64 + jb*8];
  *(float4*)(sp+0) = make_float4(acc[0], acc[1], acc[2], acc[3]);
  *(float4*)(sp+4) = make_float4(acc[4], acc[5], acc[6], acc[7]);
  #pragma unroll
  for (int k = 0; k < 8; k++){ sb[nl][jb*8+k] = acc[k]; qb[nl][jb*8+k] = acc[k]*acc[k]; }
  __syncthreads();
  if (t < 64){
    float S = 0.f, Q = 0.f;
    #pragma unroll 4
    for (int nn = 0; nn < 32; nn++){ S += sb[nn][t]; Q += qb[nn][t]; }
    psum[blockIdx.x*64 + t] = S;
    psq [blockIdx.x*64 + t] = Q;
  }
}

__global__ __launch_bounds__(1024) void k_fin2(const float* __restrict__ ps, const float* __restrict__ pq,
    const float* __restrict__ g, const float* __restrict__ be, float* __restrict__ scale, float* __restrict__ shift){
  __shared__ float rs[1024], rq[1024];
  int t = threadIdx.x, c = t & 63, gi = t >> 6;
  float s = 0.f, q = 0.f;
  for (int b = gi; b < 768; b += 16){ s += ps[b*64 + c]; q += pq[b*64 + c]; }
  rs[t] = s; rq[t] = q; __syncthreads();
  if (t < 64){
    float S = 0.f, Q = 0.f;
    #pragma unroll
    for (int gg = 0; gg < 16; gg++){ S += rs[gg*64 + t]; Q += rq[gg*64 + t]; }
    float cnt = 24576.0f;
    float mu = S / cnt;
    float var = Q / cnt - mu*mu;
    float sc = rsqrtf(var + 1e-5f) * g[t];
    scale[t] = sc;
    shift[t] = be[t] - mu * sc;
  }
}

__global__ __launch_bounds__(256) void k_update(const float* __restrict__ fea, const float* __restrict__ summed,
    const float* __restrict__ sc2, const float* __restrict__ sh2, float* __restrict__ out){
  int i = blockIdx.x*256 + threadIdx.x;
  int d = i & 63;
  float x = fea[i] + summed[i]*sc2[d] + sh2[d];
  out[i] = softplus_f(x);
}

// ================= decode, stage 1: Zfrag[b][k] = W_k @ bt^T in MFMA-fragment order =================
__global__ __launch_bounds__(256) void k_zfill(const float* __restrict__ fea, const int* __restrict__ cidx,
    const float* __restrict__ Wadj, const float* __restrict__ Wedge, bf16* __restrict__ Zfrag){
  __shared__ bf16 Wd[64][72];
  __shared__ bf16 btb[48][72];
  int bx = blockIdx.x;
  int b = bx / 11, k = bx - b*11;
  const float* Wk = (k < 6) ? (Wadj + (size_t)k*4096) : (Wedge + (size_t)(k-6)*4096);
  int t = threadIdx.x, L = t & 63, w = t >> 6;
  const int* ci = cidx + b*48;
  for (int i = t; i < 4096; i += 256) Wd[i>>6][i&63] = f2b(Wk[i]);
  for (int i = t; i < 3072; i += 256){ int r = i>>6, d = i&63; btb[r][d] = f2b(fea[(size_t)ci[r]*64 + d]); }
  __syncthreads();
  bf16* Zb = Zfrag + (size_t)b*33792 + (size_t)k*3072;
  short8v av0 = *(const short8v*)&Wd[w*16 + (L&15)][(L>>4)*8];
  short8v av1 = *(const short8v*)&Wd[w*16 + (L&15)][(L>>4)*8 + 32];
  int s = L >> 4;
  int d0 = w*16 + s*4;
  int dc = d0 >> 5, sub = (d0 >> 3) & 3, off = d0 & 7;
  #pragma unroll
  for (int nc = 0; nc < 3; nc++){
    short8v bv0 = *(const short8v*)&btb[nc*16 + (L&15)][(L>>4)*8];
    short8v bv1 = *(const short8v*)&btb[nc*16 + (L&15)][(L>>4)*8 + 32];
    f32x4 z = (f32x4){0.f,0.f,0.f,0.f};
    z = __builtin_amdgcn_mfma_f32_16x16x32_bf16(av0, bv0, z, 0, 0, 0);
    z = __builtin_amdgcn_mfma_f32_16x16x32_bf16(av1, bv1, z, 0, 0, 0);
    bf16 zp[4];
    #pragma unroll
    for (int r = 0; r < 4; r++) zp[r] = f2b(z[r]);
    *(uint2*)&Zb[(size_t)((nc*2 + dc)*64 + sub*16 + (L&15))*8 + off] = *(const uint2*)zp;
  }
}

__global__ __launch_bounds__(256) void k_prep_atom(const float* __restrict__ Watom, bf16* __restrict__ Waf){
  int t = threadIdx.x;
  for (int i = t; i < 768; i += 256){
    int oc = i >> 7, rem = i & 127, dc = rem >> 6, L = rem & 63;
    int o = oc*16 + (L & 15);
    int dbase = (L >> 4)*8 + dc*32;
    bf16 tmp[8];
    #pragma unroll
    for (int j = 0; j < 8; j++) tmp[j] = f2b(o < 92 ? Watom[(size_t)o*64 + dbase + j] : 0.f);
    *(uint4*)&Waf[(size_t)i * 8] = *(const uint4*)tmp;
  }
}

// ================= decode, stage 2: pair scores + fc + log_softmax + atom head =================
__global__ __launch_bounds__(256) void k_pair(const float* __restrict__ fea, const int* __restrict__ cidx,
    const bf16* __restrict__ Zfrag, const bf16* __restrict__ Waf,
    const float* __restrict__ badj, const float* __restrict__ Wfc1, const float* __restrict__ bfc1,
    const float* __restrict__ bedge, const float* __restrict__ Wfc2, const float* __restrict__ bfc2,
    const float* __restrict__ batom, float* __restrict__ out){
  __shared__ float cst[84];
  int t = threadIdx.x, L = t & 63, w = t >> 6;
  int bx = blockIdx.x, b = bx / 3, mr = bx - b*3;
  if (t < 36) cst[t] = Wfc1[t];
  else if (t < 42) cst[t] = bfc1[t-36];
  else if (t < 48) cst[t] = badj[t-42];
  else if (t < 73) cst[t] = Wfc2[t-48];
  else if (t < 78) cst[t] = bfc2[t-73];
  else if (t < 83) cst[t] = bedge[t-78];
  int arow = cidx[b*48 + mr*16 + (L & 15)];
  const float* fr = fea + (size_t)arow*64 + (L >> 4)*8;
  float fa[16];
  *(float4*)(fa+0)  = *(const float4*)(fr+0);
  *(float4*)(fa+4)  = *(const float4*)(fr+4);
  *(float4*)(fa+8)  = *(const float4*)(fr+32);
  *(float4*)(fa+12) = *(const float4*)(fr+36);
  bf16 ab[16];
  #pragma unroll
  for (int j = 0; j < 16; j++) ab[j] = f2b(fa[j]);
  short8v av0 = *(const short8v*)&ab[0];
  short8v av1 = *(const short8v*)&ab[8];
  __syncthreads();

  if (w < 3){
    const bf16* Zb = Zfrag + (size_t)b*33792 + (size_t)w*1024;
    f32x4 acc[11];
    #pragma unroll
    for (int k = 0; k < 11; k++){
      const bf16* zp = Zb + (size_t)k*3072;
      short8v bv0 = *(const short8v*)&zp[(size_t)L*8];
      short8v bv1 = *(const short8v*)&zp[512 + (size_t)L*8];
      f32x4 a = (f32x4){0.f,0.f,0.f,0.f};
      a = __builtin_amdgcn_mfma_f32_16x16x32_bf16(av0, bv0, a, 0, 0, 0);
      a = __builtin_amdgcn_mfma_f32_16x16x32_bf16(av1, bv1, a, 0, 0, 0);
      acc[k] = a;
    }
    size_t obase = (size_t)b * 13824;
    size_t fbase = 9338880ull + (size_t)b * 11520;
    int n = w*16 + (L & 15);
    #pragma unroll
    for (int r = 0; r < 4; r++){
      int m = mr*16 + (L >> 4)*4 + r;
      float sv[6];
      #pragma unroll
      for (int k = 0; k < 6; k++) sv[k] = acc[k][r] + cst[42 + k];
      float v[6]; float mx = -1e30f;
      #pragma unroll
      for (int i2 = 0; i2 < 6; i2++){
        float a = cst[36 + i2];
        #pragma unroll
        for (int j2 = 0; j2 < 6; j2++) a += cst[i2*6 + j2] * sv[j2];
        v[i2] = a; mx = fmaxf(mx, a);
      }
      float lse = 0.f;
      #pragma unroll
      for (int i2 = 0; i2 < 6; i2++) lse += __expf(v[i2] - mx);
      lse = mx + __logf(lse);
      size_t po = obase + (size_t)(m*48 + n)*6;
      #pragma unroll
      for (int i2 = 0; i2 < 6; i2++) out[po + i2] = v[i2] - lse;
      float sf[5];
      #pragma unroll
      for (int k = 0; k < 5; k++) sf[k] = acc[6 + k][r] + cst[78 + k];
      size_t pf = fbase + (size_t)(m*48 + n)*5;
      #pragma unroll
      for (int i2 = 0; i2 < 5; i2++){
        float a = cst[73 + i2];
        #pragma unroll
        for (int j2 = 0; j2 < 5; j2++) a += cst[48 + i2*5 + j2] * sf[j2];
        out[pf + i2] = a;
      }
    }
  } else {
    size_t abase = 7077888ull + (size_t)b * 4416;
    #pragma unroll
    for (int oc = 0; oc < 6; oc++){
      short8v bv0 = *(const short8v*)&Waf[(size_t)((oc*2 + 0)*64 + L)*8];
      short8v bv1 = *(const short8v*)&Waf[(size_t)((oc*2 + 1)*64 + L)*8];
      f32x4 a = (f32x4){0.f,0.f,0.f,0.f};
      a = __builtin_amdgcn_mfma_f32_16x16x32_bf16(av0, bv0, a, 0, 0, 0);
      a = __builtin_amdgcn_mfma_f32_16x16x32_bf16(av1, bv1, a, 0, 0, 0);
      int o = oc*16 + (L & 15);
      if (o < 92){
        float bb2 = batom[o];
        #pragma unroll
        for (int r = 0; r < 4; r++){
          int m = mr*16 + (L >> 4)*4 + r;
          out[abase + (size_t)m*92 + o] = a[r] + bb2;
        }
      }
    }
  }
}

extern "C" void kernel_launch(void* const* d_in, const int* in_sizes, int n_in,
                              void* d_out, int out_size, void* d_ws, size_t ws_size,
                              hipStream_t stream) {
  const float* atom_fea = (const float*)d_in[0];
  const float* nbr_fea  = (const float*)d_in[1];
  const int*   nbr_idx  = (const int*)d_in[2];
  const int*   cidx     = (const int*)d_in[3];
  const float* W_emb    = (const float*)d_in[4];
  const float* W_full   = (const float*)d_in[5];
  const float* b_full   = (const float*)d_in[6];
  const float* g1       = (const float*)d_in[7];
  const float* be1      = (const float*)d_in[8];
  const float* g2       = (const float*)d_in[9];
  const float* be2      = (const float*)d_in[10];
  const float* W_adj    = (const float*)d_in[11];
  const float* b_adj    = (const float*)d_in[12];
  const float* W_fc1    = (const float*)d_in[13];
  const float* b_fc1    = (const float*)d_in[14];
  const float* W_edge   = (const float*)d_in[15];
  const float* b_edge   = (const float*)d_in[16];
  const float* W_fc2    = (const float*)d_in[17];
  const float* b_fc2    = (const float*)d_in[18];
  const float* W_atom   = (const float*)d_in[19];
  const float* b_atom   = (const float*)d_in[20];

  char* ws = (char*)d_ws;
  float* fea    = (float*)(ws);                  // 6,291,456   (in-place update; no feaB)
  float* P      = (float*)(ws + 6291456);        // 25,165,824
  float* summed = (float*)(ws + 31457280);       // 6,291,456
  float* p1     = (float*)(ws + 37748736);       // 1,048,576 (2048 x 128)
  float* p1q    = (float*)(ws + 38797312);       // 1,048,576
  float* p2     = (float*)(ws + 39845888);       // 196,608 (768 x 64)
  float* p2q    = (float*)(ws + 40042496);       // 196,608
  float* sc1    = (float*)(ws + 40239104);       // 512
  float* sh1    = (float*)(ws + 40239616);       // 512
  float* sc2    = (float*)(ws + 40240128);       // 256
  float* sh2    = (float*)(ws + 40240384);       // 256
  bf16*  gated  = (bf16*)(ws + 40240640);        // 75,497,472 (end ~115.7 MB)
  bf16*  Zfrag  = (bf16*)(ws + 40240640);        // 34,603,008 — reuses gated (dead by decode)
  bf16*  Waf    = (bf16*)(ws + 74843648);        // 12,288 — after Zfrag, inside gated region
  float* out    = (float*)d_out;

  k_embed<<<384, 256, 0, stream>>>(atom_fea, W_emb, fea);

  for (int l = 0; l < 3; l++){
    const float* Wl = W_full + (size_t)l * 128 * 169;
    k_proj<<<384, 256, 0, stream>>>(fea, Wl, P);
    k_gate<<<2048, 256, 0, stream>>>(P, nbr_fea, nbr_idx, Wl, b_full + l*128, gated, p1, p1q);
    k_fin1<<<1, 1024, 0, stream>>>(p1, p1q, g1 + l*128, be1 + l*128, sc1, sh1);
    k_pool<<<768, 256, 0, stream>>>(gated, sc1, sh1, summed, p2, p2q);
    k_fin2<<<1, 1024, 0, stream>>>(p2, p2q, g2 + l*64, be2 + l*64, sc2, sh2);
    k_update<<<6144, 256, 0, stream>>>(fea, summed, sc2, sh2, fea);
  }

  k_prep_atom<<<1, 256, 0, stream>>>(W_atom, Waf);
  k_zfill<<<5632, 256, 0, stream>>>(fea, cidx, W_adj, W_edge, Zfrag);
  k_pair<<<1536, 256, 0, stream>>>(fea, cidx, Zfrag, Waf, b_adj, W_fc1, b_fc1,
                                   b_edge, W_fc2, b_fc2, b_atom, out);
}

// Round 9
// 624.688 us; speedup vs baseline: 1.2286x; 1.2286x over previous
//
#include <hip/hip_runtime.h>
#include <hip/hip_bf16.h>

typedef __hip_bfloat16 bf16;
typedef __attribute__((ext_vector_type(8))) short short8v;
typedef __attribute__((ext_vector_type(4))) float f32x4;

__device__ __forceinline__ float b2f(bf16 v){ return __bfloat162float(v); }
__device__ __forceinline__ bf16 f2b(float v){ return __float2bfloat16(v); }
__device__ __forceinline__ float softplus_f(float x){ return (x > 15.f) ? x : __logf(1.f + __expf(x)); }
__device__ __forceinline__ float sigmoid_f(float x){ return 1.f / (1.f + __expf(-x)); }

// ---------------- embedding: fea[n,d] = sum_k A[n,k] * W_emb[d,k] ----------------
__global__ __launch_bounds__(256) void k_embed(const float* __restrict__ A, const float* __restrict__ W,
                                               float* __restrict__ fea){
  __shared__ float Wl[92][64];
  __shared__ float Al[64][92];
  int t = threadIdx.x;
  int base = blockIdx.x * 64;
  for (int i = t; i < 92*64; i += 256){ int d = i / 92, k = i - d*92; Wl[k][d] = W[d*92 + k]; }
  for (int i = t; i < 64*92; i += 256){ int a = i / 92, k = i - a*92; Al[a][k] = A[(size_t)(base+a)*92 + k]; }
  __syncthreads();
  int d = t & 63, slot = t >> 6;
  for (int a = slot; a < 64; a += 4){
    float acc = 0.f;
    #pragma unroll 4
    for (int k = 0; k < 92; k++) acc += Al[a][k] * Wl[k][d];
    fea[(size_t)(base+a)*64 + d] = acc;
  }
}

// ---------------- proj via MFMA: P[a][c] = fea[a,:].Wcat[c,:] (round-7 proven win) ----------------
__global__ __launch_bounds__(256) void k_proj(const float* __restrict__ fea, const float* __restrict__ W,
                                              float* __restrict__ P){
  __shared__ bf16 Fb[64][72];
  __shared__ bf16 Wb[256][72];
  int t = threadIdx.x, L = t & 63, w = t >> 6;
  int base = blockIdx.x * 64;
  for (int i = t; i < 4096; i += 256){ int r = i >> 6, d = i & 63;
    Fb[r][d] = f2b(fea[(size_t)(base+r)*64 + d]); }
  for (int i = t; i < 16384; i += 256){ int rw = i >> 6, e = i & 63;
    Wb[rw][e] = f2b(W[(size_t)(rw & 127)*169 + ((rw < 128) ? 0 : 64) + e]); }
  __syncthreads();
  short8v av0 = *(const short8v*)&Fb[w*16 + (L&15)][(L>>4)*8];
  short8v av1 = *(const short8v*)&Fb[w*16 + (L&15)][(L>>4)*8 + 32];
  #pragma unroll
  for (int tc = 0; tc < 16; tc++){
    short8v bv0 = *(const short8v*)&Wb[tc*16 + (L&15)][(L>>4)*8];
    short8v bv1 = *(const short8v*)&Wb[tc*16 + (L&15)][(L>>4)*8 + 32];
    f32x4 acc = (f32x4){0.f,0.f,0.f,0.f};
    acc = __builtin_amdgcn_mfma_f32_16x16x32_bf16(av0, bv0, acc, 0, 0, 0);
    acc = __builtin_amdgcn_mfma_f32_16x16x32_bf16(av1, bv1, acc, 0, 0, 0);
    #pragma unroll
    for (int r = 0; r < 4; r++){
      int m = base + w*16 + (L>>4)*4 + r;
      P[(size_t)m*256 + tc*16 + (L&15)] = acc[r];
    }
  }
}

// ---------------- gate (round-3 exact, FROZEN): P_self + P_nbr[idx] + nbr_fea.W_e + b ----------------
__global__ __launch_bounds__(256) void k_gate(const float* __restrict__ P, const float* __restrict__ nbrF,
    const int* __restrict__ idx, const float* __restrict__ W, const float* __restrict__ bg,
    bf16* __restrict__ gated, float* __restrict__ psum, float* __restrict__ psq){
  __shared__ float nf[24][44];
  __shared__ int jrow[24];
  __shared__ float red[256];
  int t = threadIdx.x;
  int slot = t >> 7, c = t & 127;
  float wreg[41];
  #pragma unroll
  for (int e = 0; e < 41; e++) wreg[e] = W[(size_t)c*169 + 128 + e];
  float bv = bg[c];
  float s = 0.f, q = 0.f;
  int rbase = blockIdx.x * 288;
  for (int st = 0; st < 12; st++){
    int row0 = rbase + st*24;
    __syncthreads();
    for (int i = t; i < 24*41; i += 256){ int rr = i / 41, e = i - rr*41; nf[rr][e] = nbrF[(size_t)(row0+rr)*41 + e]; }
    if (t < 24) jrow[t] = idx[row0 + t];
    __syncthreads();
    int a = row0/12 + slot;
    float ps = P[(size_t)a*256 + c] + bv;
    #pragma unroll
    for (int m = 0; m < 12; m++){
      int rr = slot*12 + m;
      int j = jrow[rr];
      float acc = ps + P[(size_t)j*256 + 128 + c];
      #pragma unroll
      for (int eb = 0; eb < 10; eb++){
        float4 nv = *(const float4*)&nf[rr][eb*4];
        acc += nv.x*wreg[eb*4] + nv.y*wreg[eb*4+1] + nv.z*wreg[eb*4+2] + nv.w*wreg[eb*4+3];
      }
      acc += nf[rr][40] * wreg[40];
      gated[(size_t)(row0+rr)*128 + c] = f2b(acc);
      s += acc; q += acc*acc;
    }
  }
  red[t] = s; __syncthreads();
  if (t < 128) psum[blockIdx.x*128 + t] = red[t] + red[t+128];
  __syncthreads(); red[t] = q; __syncthreads();
  if (t < 128) psq[blockIdx.x*128 + t] = red[t] + red[t+128];
}

__global__ __launch_bounds__(1024) void k_fin1(const float* __restrict__ ps, const float* __restrict__ pq,
    const float* __restrict__ g, const float* __restrict__ be, float* __restrict__ scale, float* __restrict__ shift){
  __shared__ float rs[1024], rq[1024];
  int t = threadIdx.x, c = t & 127, gi = t >> 7;
  float s = 0.f, q = 0.f;
  for (int b = gi; b < 1024; b += 8){ s += ps[b*128 + c]; q += pq[b*128 + c]; }
  rs[t] = s; rq[t] = q; __syncthreads();
  if (t < 128){
    float S = 0.f, Q = 0.f;
    #pragma unroll
    for (int gg = 0; gg < 8; gg++){ S += rs[gg*128 + t]; Q += rq[gg*128 + t]; }
    float cnt = 294912.0f;
    float mu = S / cnt;
    float var = Q / cnt - mu*mu;
    float sc = rsqrtf(var + 1e-5f) * g[t];
    scale[t] = sc;
    shift[t] = be[t] - mu * sc;
  }
}

// ---------------- pool: vectorized (short8) normalize + sigmoid*softplus + sum over M ----------------
__global__ __launch_bounds__(256) void k_pool(const bf16* __restrict__ gated, const float* __restrict__ scale,
    const float* __restrict__ shift, float* __restrict__ summed, float* __restrict__ psum, float* __restrict__ psq){
  __shared__ float sc[128], sh[128];
  __shared__ float sb[32][65], qb[32][65];
  int t = threadIdx.x;
  if (t < 128){ sc[t] = scale[t]; sh[t] = shift[t]; }
  __syncthreads();
  int nl = t >> 3, jb = t & 7;
  int n = blockIdx.x*32 + nl;
  const bf16* gp = gated + (size_t)n*1536 + jb*8;
  float sc1r[8], sh1r[8], sc2r[8], sh2r[8];
  #pragma unroll
  for (int k = 0; k < 8; k++){
    int d = jb*8 + k;
    sc1r[k] = sc[d]; sh1r[k] = sh[d]; sc2r[k] = sc[64+d]; sh2r[k] = sh[64+d];
  }
  float acc[8];
  #pragma unroll
  for (int k = 0; k < 8; k++) acc[k] = 0.f;
  #pragma unroll
  for (int m = 0; m < 12; m++){
    short8v fv = *(const short8v*)(gp + m*128);
    short8v cv = *(const short8v*)(gp + m*128 + 64);
    #pragma unroll
    for (int k = 0; k < 8; k++){
      bf16 fb, cb;
      *(short*)&fb = fv[k]; *(short*)&cb = cv[k];
      float y1 = b2f(fb) * sc1r[k] + sh1r[k];
      float y2 = b2f(cb) * sc2r[k] + sh2r[k];
      acc[k] += sigmoid_f(y1) * softplus_f(y2);
    }
  }
  float* sp = &summed[(size_t)n*64 + jb*8];
  *(float4*)(sp+0) = make_float4(acc[0], acc[1], acc[2], acc[3]);
  *(float4*)(sp+4) = make_float4(acc[4], acc[5], acc[6], acc[7]);
  #pragma unroll
  for (int k = 0; k < 8; k++){ sb[nl][jb*8+k] = acc[k]; qb[nl][jb*8+k] = acc[k]*acc[k]; }
  __syncthreads();
  if (t < 64){
    float S = 0.f, Q = 0.f;
    #pragma unroll 4
    for (int nn = 0; nn < 32; nn++){ S += sb[nn][t]; Q += qb[nn][t]; }
    psum[blockIdx.x*64 + t] = S;
    psq [blockIdx.x*64 + t] = Q;
  }
}

__global__ __launch_bounds__(1024) void k_fin2(const float* __restrict__ ps, const float* __restrict__ pq,
    const float* __restrict__ g, const float* __restrict__ be, float* __restrict__ scale, float* __restrict__ shift){
  __shared__ float rs[1024], rq[1024];
  int t = threadIdx.x, c = t & 63, gi = t >> 6;
  float s = 0.f, q = 0.f;
  for (int b = gi; b < 768; b += 16){ s += ps[b*64 + c]; q += pq[b*64 + c]; }
  rs[t] = s; rq[t] = q; __syncthreads();
  if (t < 64){
    float S = 0.f, Q = 0.f;
    #pragma unroll
    for (int gg = 0; gg < 16; gg++){ S += rs[gg*64 + t]; Q += rq[gg*64 + t]; }
    float cnt = 24576.0f;
    float mu = S / cnt;
    float var = Q / cnt - mu*mu;
    float sc = rsqrtf(var + 1e-5f) * g[t];
    scale[t] = sc;
    shift[t] = be[t] - mu * sc;
  }
}

__global__ __launch_bounds__(256) void k_update(const float* __restrict__ fea, const float* __restrict__ summed,
    const float* __restrict__ sc2, const float* __restrict__ sh2, float* __restrict__ out){
  int i = blockIdx.x*256 + threadIdx.x;
  int d = i & 63;
  float x = fea[i] + summed[i]*sc2[d] + sh2[d];
  out[i] = softplus_f(x);
}

// ================= decode, stage 1: Zfrag[b][k] = W_k @ bt^T in MFMA-fragment order =================
__global__ __launch_bounds__(256) void k_zfill(const float* __restrict__ fea, const int* __restrict__ cidx,
    const float* __restrict__ Wadj, const float* __restrict__ Wedge, bf16* __restrict__ Zfrag){
  __shared__ bf16 Wd[64][72];
  __shared__ bf16 btb[48][72];
  int bx = blockIdx.x;
  int b = bx / 11, k = bx - b*11;
  const float* Wk = (k < 6) ? (Wadj + (size_t)k*4096) : (Wedge + (size_t)(k-6)*4096);
  int t = threadIdx.x, L = t & 63, w = t >> 6;
  const int* ci = cidx + b*48;
  for (int i = t; i < 4096; i += 256) Wd[i>>6][i&63] = f2b(Wk[i]);
  for (int i = t; i < 3072; i += 256){ int r = i>>6, d = i&63; btb[r][d] = f2b(fea[(size_t)ci[r]*64 + d]); }
  __syncthreads();
  bf16* Zb = Zfrag + (size_t)b*33792 + (size_t)k*3072;
  short8v av0 = *(const short8v*)&Wd[w*16 + (L&15)][(L>>4)*8];
  short8v av1 = *(const short8v*)&Wd[w*16 + (L&15)][(L>>4)*8 + 32];
  int s = L >> 4;
  int d0 = w*16 + s*4;
  int dc = d0 >> 5, sub = (d0 >> 3) & 3, off = d0 & 7;
  #pragma unroll
  for (int nc = 0; nc < 3; nc++){
    short8v bv0 = *(const short8v*)&btb[nc*16 + (L&15)][(L>>4)*8];
    short8v bv1 = *(const short8v*)&btb[nc*16 + (L&15)][(L>>4)*8 + 32];
    f32x4 z = (f32x4){0.f,0.f,0.f,0.f};
    z = __builtin_amdgcn_mfma_f32_16x16x32_bf16(av0, bv0, z, 0, 0, 0);
    z = __builtin_amdgcn_mfma_f32_16x16x32_bf16(av1, bv1, z, 0, 0, 0);
    bf16 zp[4];
    #pragma unroll
    for (int r = 0; r < 4; r++) zp[r] = f2b(z[r]);
    *(uint2*)&Zb[(size_t)((nc*2 + dc)*64 + sub*16 + (L&15))*8 + off] = *(const uint2*)zp;
  }
}

__global__ __launch_bounds__(256) void k_prep_atom(const float* __restrict__ Watom, bf16* __restrict__ Waf){
  int t = threadIdx.x;
  for (int i = t; i < 768; i += 256){
    int oc = i >> 7, rem = i & 127, dc = rem >> 6, L = rem & 63;
    int o = oc*16 + (L & 15);
    int dbase = (L >> 4)*8 + dc*32;
    bf16 tmp[8];
    #pragma unroll
    for (int j = 0; j < 8; j++) tmp[j] = f2b(o < 92 ? Watom[(size_t)o*64 + dbase + j] : 0.f);
    *(uint4*)&Waf[(size_t)i * 8] = *(const uint4*)tmp;
  }
}

// ================= decode, stage 2: pair scores + fc + log_softmax + atom head =================
__global__ __launch_bounds__(256) void k_pair(const float* __restrict__ fea, const int* __restrict__ cidx,
    const bf16* __restrict__ Zfrag, const bf16* __restrict__ Waf,
    const float* __restrict__ badj, const float* __restrict__ Wfc1, const float* __restrict__ bfc1,
    const float* __restrict__ bedge, const float* __restrict__ Wfc2, const float* __restrict__ bfc2,
    const float* __restrict__ batom, float* __restrict__ out){
  __shared__ float cst[84];
  int t = threadIdx.x, L = t & 63, w = t >> 6;
  int bx = blockIdx.x, b = bx / 3, mr = bx - b*3;
  if (t < 36) cst[t] = Wfc1[t];
  else if (t < 42) cst[t] = bfc1[t-36];
  else if (t < 48) cst[t] = badj[t-42];
  else if (t < 73) cst[t] = Wfc2[t-48];
  else if (t < 78) cst[t] = bfc2[t-73];
  else if (t < 83) cst[t] = bedge[t-78];
  int arow = cidx[b*48 + mr*16 + (L & 15)];
  const float* fr = fea + (size_t)arow*64 + (L >> 4)*8;
  float fa[16];
  *(float4*)(fa+0)  = *(const float4*)(fr+0);
  *(float4*)(fa+4)  = *(const float4*)(fr+4);
  *(float4*)(fa+8)  = *(const float4*)(fr+32);
  *(float4*)(fa+12) = *(const float4*)(fr+36);
  bf16 ab[16];
  #pragma unroll
  for (int j = 0; j < 16; j++) ab[j] = f2b(fa[j]);
  short8v av0 = *(const short8v*)&ab[0];
  short8v av1 = *(const short8v*)&ab[8];
  __syncthreads();

  if (w < 3){
    const bf16* Zb = Zfrag + (size_t)b*33792 + (size_t)w*1024;
    f32x4 acc[11];
    #pragma unroll
    for (int k = 0; k < 11; k++){
      const bf16* zp = Zb + (size_t)k*3072;
      short8v bv0 = *(const short8v*)&zp[(size_t)L*8];
      short8v bv1 = *(const short8v*)&zp[512 + (size_t)L*8];
      f32x4 a = (f32x4){0.f,0.f,0.f,0.f};
      a = __builtin_amdgcn_mfma_f32_16x16x32_bf16(av0, bv0, a, 0, 0, 0);
      a = __builtin_amdgcn_mfma_f32_16x16x32_bf16(av1, bv1, a, 0, 0, 0);
      acc[k] = a;
    }
    size_t obase = (size_t)b * 13824;
    size_t fbase = 9338880ull + (size_t)b * 11520;
    int n = w*16 + (L & 15);
    #pragma unroll
    for (int r = 0; r < 4; r++){
      int m = mr*16 + (L >> 4)*4 + r;
      float sv[6];
      #pragma unroll
      for (int k = 0; k < 6; k++) sv[k] = acc[k][r] + cst[42 + k];
      float v[6]; float mx = -1e30f;
      #pragma unroll
      for (int i2 = 0; i2 < 6; i2++){
        float a = cst[36 + i2];
        #pragma unroll
        for (int j2 = 0; j2 < 6; j2++) a += cst[i2*6 + j2] * sv[j2];
        v[i2] = a; mx = fmaxf(mx, a);
      }
      float lse = 0.f;
      #pragma unroll
      for (int i2 = 0; i2 < 6; i2++) lse += __expf(v[i2] - mx);
      lse = mx + __logf(lse);
      size_t po = obase + (size_t)(m*48 + n)*6;
      #pragma unroll
      for (int i2 = 0; i2 < 6; i2++) out[po + i2] = v[i2] - lse;
      float sf[5];
      #pragma unroll
      for (int k = 0; k < 5; k++) sf[k] = acc[6 + k][r] + cst[78 + k];
      size_t pf = fbase + (size_t)(m*48 + n)*5;
      #pragma unroll
      for (int i2 = 0; i2 < 5; i2++){
        float a = cst[73 + i2];
        #pragma unroll
        for (int j2 = 0; j2 < 5; j2++) a += cst[48 + i2*5 + j2] * sf[j2];
        out[pf + i2] = a;
      }
    }
  } else {
    size_t abase = 7077888ull + (size_t)b * 4416;
    #pragma unroll
    for (int oc = 0; oc < 6; oc++){
      short8v bv0 = *(const short8v*)&Waf[(size_t)((oc*2 + 0)*64 + L)*8];
      short8v bv1 = *(const short8v*)&Waf[(size_t)((oc*2 + 1)*64 + L)*8];
      f32x4 a = (f32x4){0.f,0.f,0.f,0.f};
      a = __builtin_amdgcn_mfma_f32_16x16x32_bf16(av0, bv0, a, 0, 0, 0);
      a = __builtin_amdgcn_mfma_f32_16x16x32_bf16(av1, bv1, a, 0, 0, 0);
      int o = oc*16 + (L & 15);
      if (o < 92){
        float bb2 = batom[o];
        #pragma unroll
        for (int r = 0; r < 4; r++){
          int m = mr*16 + (L >> 4)*4 + r;
          out[abase + (size_t)m*92 + o] = a[r] + bb2;
        }
      }
    }
  }
}

extern "C" void kernel_launch(void* const* d_in, const int* in_sizes, int n_in,
                              void* d_out, int out_size, void* d_ws, size_t ws_size,
                              hipStream_t stream) {
  const float* atom_fea = (const float*)d_in[0];
  const float* nbr_fea  = (const float*)d_in[1];
  const int*   nbr_idx  = (const int*)d_in[2];
  const int*   cidx     = (const int*)d_in[3];
  const float* W_emb    = (const float*)d_in[4];
  const float* W_full   = (const float*)d_in[5];
  const float* b_full   = (const float*)d_in[6];
  const float* g1       = (const float*)d_in[7];
  const float* be1      = (const float*)d_in[8];
  const float* g2       = (const float*)d_in[9];
  const float* be2      = (const float*)d_in[10];
  const float* W_adj    = (const float*)d_in[11];
  const float* b_adj    = (const float*)d_in[12];
  const float* W_fc1    = (const float*)d_in[13];
  const float* b_fc1    = (const float*)d_in[14];
  const float* W_edge   = (const float*)d_in[15];
  const float* b_edge   = (const float*)d_in[16];
  const float* W_fc2    = (const float*)d_in[17];
  const float* b_fc2    = (const float*)d_in[18];
  const float* W_atom   = (const float*)d_in[19];
  const float* b_atom   = (const float*)d_in[20];

  char* ws = (char*)d_ws;
  float* feaA   = (float*)(ws);                  // 6,291,456
  float* feaB   = (float*)(ws + 6291456);        // 6,291,456
  float* P      = (float*)(ws + 12582912);       // 25,165,824
  float* summed = (float*)(ws + 37748736);       // 6,291,456
  float* p1     = (float*)(ws + 44040192);       // 524,288 (1024 x 128)
  float* p1q    = (float*)(ws + 44630016);       // 524,288
  float* p2     = (float*)(ws + 45219840);       // 196,608 (768 x 64)
  float* p2q    = (float*)(ws + 45481984);       // 196,608
  float* sc1    = (float*)(ws + 45744128);
  float* sh1    = (float*)(ws + 45744640);
  float* sc2    = (float*)(ws + 45745152);
  float* sh2    = (float*)(ws + 45745408);
  bf16*  gated  = (bf16*)(ws + 45745664);        // 75,497,472
  bf16*  Zfrag  = (bf16*)(ws + 45745664);        // 34,603,008 — reuses gated (dead by decode)
  bf16*  Waf    = (bf16*)(ws + 80348672);        // 12,288
  float* out    = (float*)d_out;

  k_embed<<<384, 256, 0, stream>>>(atom_fea, W_emb, feaA);

  float* cur = feaA; float* nxt = feaB;
  for (int l = 0; l < 3; l++){
    const float* Wl = W_full + (size_t)l * 128 * 169;
    k_proj<<<384, 256, 0, stream>>>(cur, Wl, P);
    k_gate<<<1024, 256, 0, stream>>>(P, nbr_fea, nbr_idx, Wl, b_full + l*128, gated, p1, p1q);
    k_fin1<<<1, 1024, 0, stream>>>(p1, p1q, g1 + l*128, be1 + l*128, sc1, sh1);
    k_pool<<<768, 256, 0, stream>>>(gated, sc1, sh1, summed, p2, p2q);
    k_fin2<<<1, 1024, 0, stream>>>(p2, p2q, g2 + l*64, be2 + l*64, sc2, sh2);
    k_update<<<6144, 256, 0, stream>>>(cur, summed, sc2, sh2, nxt);
    float* tmp = cur; cur = nxt; nxt = tmp;
  }

  k_prep_atom<<<1, 256, 0, stream>>>(W_atom, Waf);
  k_zfill<<<5632, 256, 0, stream>>>(cur, cidx, W_adj, W_edge, Zfrag);
  k_pair<<<1536, 256, 0, stream>>>(cur, cidx, Zfrag, Waf, b_adj, W_fc1, b_fc1,
                                   b_edge, W_fc2, b_fc2, b_atom, out);
}